// Round 7
// baseline (1348.686 us; speedup 1.0000x reference)
//
#include <hip/hip_runtime.h>
#include <cmath>

#define B_   2048
#define S_   60
#define NTOK (B_*S_)
#define IND_ 211
#define D_   192
#define H_   6
#define DK_  32
#define L_   3
#define DFF_ 768
#define NC_  35
#define DH_  96

typedef unsigned short us_t;
typedef us_t us8 __attribute__((ext_vector_type(8)));
typedef us_t us4 __attribute__((ext_vector_type(4)));
typedef short sh8 __attribute__((ext_vector_type(8)));
typedef float f4 __attribute__((ext_vector_type(4)));

#define MFMA(a, b, cc) __builtin_amdgcn_mfma_f32_16x16x32_bf16((a), (b), (cc), 0, 0, 0)
#define ZACC(A, M, N) \
    for (int _i = 0; _i < (M); ++_i) \
        for (int _j = 0; _j < (N); ++_j) { \
            A[_i][_j][0] = 0.f; A[_i][_j][1] = 0.f; A[_i][_j][2] = 0.f; A[_i][_j][3] = 0.f; }
#define ZACC1(A, N) \
    for (int _j = 0; _j < (N); ++_j) { \
        A[_j][0] = 0.f; A[_j][1] = 0.f; A[_j][2] = 0.f; A[_j][3] = 0.f; }

__device__ __forceinline__ float bf2f(us_t u) {
    union { unsigned int i; float f; } v; v.i = ((unsigned int)u) << 16; return v.f;
}
__device__ __forceinline__ us_t f2bf(float f) {
    union { float f; unsigned int i; } v; v.f = f;
    unsigned int r = v.i + 0x7fffu + ((v.i >> 16) & 1u);
    return (us_t)(r >> 16);
}
// fast tanh-gelu: |err| < 1e-3 vs exact erf-gelu, well under bf16 rounding
__device__ __forceinline__ float gelu_f(float v) {
    float u = v * (0.7978845608f + 0.0356774081f * v * v);
    float e = __expf(2.f * u);
    float t = 1.f - 2.f / (e + 1.f);       // overflow-safe tanh
    return 0.5f * v * (1.f + t);
}
__device__ __forceinline__ void gld16(const us_t* g, us_t* s) {
    __builtin_amdgcn_global_load_lds(
        (const __attribute__((address_space(1))) unsigned int*)(g),
        (__attribute__((address_space(3))) unsigned int*)(s), 16, 0, 0);
}

// ---------------------------------------------------------------------------
// Weight prep (qkv/wo/inp/clf1): out[n][kp] = bf16(in[kp][n]), zero-pad Kpad.
// ---------------------------------------------------------------------------
__global__ void prep_t(const float* __restrict__ in, us_t* __restrict__ out,
                       int K, int Kpad, int N)
{
    int e = blockIdx.x * 256 + threadIdx.x;
    if (e >= N * Kpad) return;
    int n = e / Kpad, kp = e % Kpad;
    out[e] = (kp < K) ? f2bf(in[(size_t)kp * N + n]) : (us_t)0;
}

// ---------------------------------------------------------------------------
// FF weight prep: 48 K32-subtile images per layer, consumption order.
// t = cb*12 + ph*6 + s; image [192 cols][32 k] contiguous (12288 B).
// ---------------------------------------------------------------------------
__global__ void prep_ff(const float* __restrict__ W1, const float* __restrict__ W2,
                        us_t* __restrict__ WT)
{
    int e = blockIdx.x * 256 + threadIdx.x;
    if (e >= L_ * 48 * 6144) return;
    int l = e / (48 * 6144), r = e % (48 * 6144);
    int t = r / 6144, q = r % 6144;
    int col = q >> 5, kk = q & 31;
    int cb = t / 12, ph = (t / 6) & 1, s = t % 6;
    us_t v;
    if (!ph) v = f2bf(W1[((size_t)l * D_ + s * 32 + kk) * DFF_ + cb * 192 + col]);
    else     v = f2bf(W2[((size_t)l * DFF_ + cb * 192 + s * 32 + kk) * D_ + col]);
    WT[e] = v;
}

// ---------------------------------------------------------------------------
// Input projection: h = bf16(x @ W_in + b_in + pe). 64 tok/block, 4 waves.
// ---------------------------------------------------------------------------
__global__ __launch_bounds__(256) void inp_mfma(
    const float* __restrict__ x, const us_t* __restrict__ Wint,
    const float* __restrict__ b_in, const float* __restrict__ pe,
    us_t* __restrict__ h)
{
    __shared__ __align__(16) char smem[29696 + 27648];
    us_t* Xs = (us_t*)smem;              // [64][232]
    us_t* Ws = (us_t*)(smem + 29696);    // [192][72]
    const int tid = threadIdx.x;
    const int lane = tid & 63, wid = tid >> 6;
    const int g = lane >> 4, c = lane & 15;
    const int wr = wid >> 1, wc = wid & 1;
    const int row0 = blockIdx.x * 64;

    for (int e = tid; e < 64 * 224; e += 256) {
        int tok = e / 224, kp = e % 224;
        float v = (kp < IND_) ? x[(size_t)(row0 + tok) * IND_ + kp] : 0.f;
        Xs[tok * 232 + kp] = f2bf(v);
    }

    f4 acc[2][6];
    ZACC(acc, 2, 6);
    for (int pc = 0; pc < 4; ++pc) {
        __syncthreads();
        const int nk = (pc < 3) ? 64 : 32;
        const int per = nk / 8;
        for (int e = tid; e < 192 * per; e += 256) {
            int rw = e / per, v = e % per;
            *(us8*)&Ws[rw * 72 + v * 8] =
                *(const us8*)&Wint[(size_t)rw * 224 + pc * 64 + v * 8];
        }
        __syncthreads();
        for (int kk = 0; kk < nk / 32; ++kk) {
            const int ka = pc * 64 + kk * 32 + g * 8;
            const int kw = kk * 32 + g * 8;
            sh8 a0 = *(const sh8*)&Xs[(32 * wr + c) * 232 + ka];
            sh8 a1 = *(const sh8*)&Xs[(32 * wr + 16 + c) * 232 + ka];
            #pragma unroll
            for (int ni = 0; ni < 6; ++ni) {
                sh8 bf = *(const sh8*)&Ws[(96 * wc + 16 * ni + c) * 72 + kw];
                acc[0][ni] = MFMA(a0, bf, acc[0][ni]);
                acc[1][ni] = MFMA(a1, bf, acc[1][ni]);
            }
        }
    }
    #pragma unroll
    for (int ni = 0; ni < 6; ++ni) {
        const int col = 96 * wc + 16 * ni + c;
        const float bv = b_in[col];
        #pragma unroll
        for (int mi = 0; mi < 2; ++mi)
            #pragma unroll
            for (int r = 0; r < 4; ++r) {
                int tokg = row0 + 32 * wr + 16 * mi + 4 * g + r;
                int s = tokg % S_;
                float val = acc[mi][ni][r] + bv + pe[(size_t)s * D_ + col];
                h[(size_t)tokg * D_ + col] = f2bf(val);
            }
    }
}

// ---------------------------------------------------------------------------
// Fused QKV + attention + Wo + residual + LN. One 512-thread block per batch.
// ---------------------------------------------------------------------------
__global__ __launch_bounds__(512) void qkv_attn_wo(
    us_t* __restrict__ h,
    const us_t* __restrict__ Wqt, const us_t* __restrict__ Wkt,
    const us_t* __restrict__ Wvt, const us_t* __restrict__ Wot,
    const float* __restrict__ bq, const float* __restrict__ bk,
    const float* __restrict__ bv, const float* __restrict__ bo,
    const float* __restrict__ g1, const float* __restrict__ be1)
{
    __shared__ __align__(16) char smem[157696];
    us_t* Xs = (us_t*)smem;               // [64][200]
    us_t* Qs = (us_t*)(smem + 25600);     // [64][200]
    us_t* Ks = (us_t*)(smem + 51200);     // [64][200]
    us_t* Vt = (us_t*)(smem + 76800);     // [192][72] (V transposed)
    us_t* Ws = (us_t*)(smem + 104448);    // [192][72]
    us_t* P0 = (us_t*)(smem + 104448);    // [64][72] overlays Ws
    us_t* P1 = (us_t*)(smem + 113664);    // [64][72]
    us_t* Cx = (us_t*)(smem + 132096);    // [64][200]
    float* eL = (float*)(smem + 51200);   // [64][200] f32 overlays Ks+Vt

    const int tid = threadIdx.x;
    const int lane = tid & 63, wid = tid >> 6;
    const int g = lane >> 4, c = lane & 15;
    const int wr = wid >> 2, wc = wid & 3;
    us_t* hb = h + (size_t)blockIdx.x * (S_ * D_);

    for (int e = tid; e < 1536; e += 512) {
        int tok = e / 24, v = e % 24;
        us8 u = {0, 0, 0, 0, 0, 0, 0, 0};
        if (tok < S_) u = *(const us8*)&hb[(size_t)tok * D_ + v * 8];
        *(us8*)&Xs[tok * 200 + v * 8] = u;
    }

    for (int m = 0; m < 3; ++m) {
        const us_t* Wt = (m == 0) ? Wqt : (m == 1) ? Wkt : Wvt;
        const float* bb = (m == 0) ? bq : (m == 1) ? bk : bv;
        f4 acc[2][3];
        ZACC(acc, 2, 3);
        for (int pc = 0; pc < 3; ++pc) {
            __syncthreads();
            for (int e = tid; e < 1536; e += 512) {
                int rw = e >> 3, v = e & 7;
                *(us8*)&Ws[rw * 72 + v * 8] =
                    *(const us8*)&Wt[(size_t)rw * 192 + pc * 64 + v * 8];
            }
            __syncthreads();
            #pragma unroll
            for (int kk = 0; kk < 2; ++kk) {
                const int ka = pc * 64 + kk * 32 + g * 8;
                const int kw = kk * 32 + g * 8;
                sh8 a0 = *(const sh8*)&Xs[(32 * wr + c) * 200 + ka];
                sh8 a1 = *(const sh8*)&Xs[(32 * wr + 16 + c) * 200 + ka];
                #pragma unroll
                for (int ni = 0; ni < 3; ++ni) {
                    sh8 bf = *(const sh8*)&Ws[(48 * wc + 16 * ni + c) * 72 + kw];
                    acc[0][ni] = MFMA(a0, bf, acc[0][ni]);
                    acc[1][ni] = MFMA(a1, bf, acc[1][ni]);
                }
            }
        }
        #pragma unroll
        for (int ni = 0; ni < 3; ++ni) {
            const int col = 48 * wc + 16 * ni + c;
            const float bval = bb[col];
            #pragma unroll
            for (int mi = 0; mi < 2; ++mi)
                #pragma unroll
                for (int r = 0; r < 4; ++r) {
                    int tok = 32 * wr + 16 * mi + 4 * g + r;
                    us_t o = f2bf(acc[mi][ni][r] + bval);
                    if (m == 0)      Qs[tok * 200 + col] = o;
                    else if (m == 1) Ks[tok * 200 + col] = o;
                    else             Vt[col * 72 + tok] = o;
                }
        }
    }
    __syncthreads();

    const int hgrp = wid & 3;
    const int hsel = wid >> 2;
    for (int rr = 0; rr < 3; ++rr) {
        const int hh = 2 * rr + hsel;
        us_t* Pb = hsel ? P1 : P0;
        f4 sc[4];
        ZACC1(sc, 4);
        {
            const int ka = 32 * hh + g * 8;
            sh8 aq = *(const sh8*)&Qs[(16 * hgrp + c) * 200 + ka];
            #pragma unroll
            for (int ni = 0; ni < 4; ++ni) {
                sh8 bk8 = *(const sh8*)&Ks[(16 * ni + c) * 200 + ka];
                sc[ni] = MFMA(aq, bk8, sc[ni]);
            }
        }
        #pragma unroll
        for (int r = 0; r < 4; ++r) {
            float mx = -1e30f;
            #pragma unroll
            for (int ni = 0; ni < 4; ++ni) {
                float v = sc[ni][r] * 0.17677669529663687f;
                if (16 * ni + c >= S_) v = -1e30f;
                sc[ni][r] = v;
                mx = fmaxf(mx, v);
            }
            mx = fmaxf(mx, __shfl_xor(mx, 1));
            mx = fmaxf(mx, __shfl_xor(mx, 2));
            mx = fmaxf(mx, __shfl_xor(mx, 4));
            mx = fmaxf(mx, __shfl_xor(mx, 8));
            float sum = 0.f;
            #pragma unroll
            for (int ni = 0; ni < 4; ++ni) {
                float e = __expf(sc[ni][r] - mx);
                sc[ni][r] = e; sum += e;
            }
            sum += __shfl_xor(sum, 1);
            sum += __shfl_xor(sum, 2);
            sum += __shfl_xor(sum, 4);
            sum += __shfl_xor(sum, 8);
            const float inv = 1.f / sum;
            #pragma unroll
            for (int ni = 0; ni < 4; ++ni)
                Pb[(16 * hgrp + 4 * g + r) * 72 + 16 * ni + c] = f2bf(sc[ni][r] * inv);
        }
        __syncthreads();
        f4 ov[2];
        ZACC1(ov, 2);
        #pragma unroll
        for (int kk = 0; kk < 2; ++kk) {
            sh8 ap = *(const sh8*)&Pb[(16 * hgrp + c) * 72 + kk * 32 + g * 8];
            #pragma unroll
            for (int n2 = 0; n2 < 2; ++n2) {
                sh8 bv8 = *(const sh8*)&Vt[(32 * hh + 16 * n2 + c) * 72 + kk * 32 + g * 8];
                ov[n2] = MFMA(ap, bv8, ov[n2]);
            }
        }
        #pragma unroll
        for (int n2 = 0; n2 < 2; ++n2)
            #pragma unroll
            for (int r = 0; r < 4; ++r)
                Cx[(16 * hgrp + 4 * g + r) * 200 + 32 * hh + 16 * n2 + c] = f2bf(ov[n2][r]);
        __syncthreads();
    }

    f4 aw[2][3];
    ZACC(aw, 2, 3);
    for (int pc = 0; pc < 3; ++pc) {
        __syncthreads();
        for (int e = tid; e < 1536; e += 512) {
            int rw = e >> 3, v = e & 7;
            *(us8*)&Ws[rw * 72 + v * 8] =
                *(const us8*)&Wot[(size_t)rw * 192 + pc * 64 + v * 8];
        }
        __syncthreads();
        #pragma unroll
        for (int kk = 0; kk < 2; ++kk) {
            const int ka = pc * 64 + kk * 32 + g * 8;
            const int kw = kk * 32 + g * 8;
            sh8 a0 = *(const sh8*)&Cx[(32 * wr + c) * 200 + ka];
            sh8 a1 = *(const sh8*)&Cx[(32 * wr + 16 + c) * 200 + ka];
            #pragma unroll
            for (int ni = 0; ni < 3; ++ni) {
                sh8 bf = *(const sh8*)&Ws[(48 * wc + 16 * ni + c) * 72 + kw];
                aw[0][ni] = MFMA(a0, bf, aw[0][ni]);
                aw[1][ni] = MFMA(a1, bf, aw[1][ni]);
            }
        }
    }
    __syncthreads();
    #pragma unroll
    for (int ni = 0; ni < 3; ++ni) {
        const int col = 48 * wc + 16 * ni + c;
        const float bov = bo[col];
        #pragma unroll
        for (int mi = 0; mi < 2; ++mi)
            #pragma unroll
            for (int r = 0; r < 4; ++r) {
                int tok = 32 * wr + 16 * mi + 4 * g + r;
                eL[tok * 200 + col] = aw[mi][ni][r] + bov + bf2f(Xs[tok * 200 + col]);
            }
    }
    __syncthreads();
    {
        const int tok = tid >> 3, t8 = tid & 7;
        float vals[24], sum = 0.f, ssq = 0.f;
        #pragma unroll
        for (int jv = 0; jv < 6; ++jv) {
            float4 v4 = *(const float4*)&eL[tok * 200 + t8 * 24 + jv * 4];
            vals[jv*4+0] = v4.x; vals[jv*4+1] = v4.y; vals[jv*4+2] = v4.z; vals[jv*4+3] = v4.w;
            sum += v4.x + v4.y + v4.z + v4.w;
            ssq += v4.x*v4.x + v4.y*v4.y + v4.z*v4.z + v4.w*v4.w;
        }
        sum += __shfl_xor(sum, 1); sum += __shfl_xor(sum, 2); sum += __shfl_xor(sum, 4);
        ssq += __shfl_xor(ssq, 1); ssq += __shfl_xor(ssq, 2); ssq += __shfl_xor(ssq, 4);
        const float mean = sum * (1.f / D_);
        const float var  = ssq * (1.f / D_) - mean * mean;
        const float rstd = rsqrtf(var + 1e-5f);
        if (tok < S_) {
            #pragma unroll
            for (int jv = 0; jv < 6; ++jv) {
                us4 o4;
                #pragma unroll
                for (int j = 0; j < 4; ++j) {
                    int col = t8 * 24 + jv * 4 + j;
                    o4[j] = f2bf((vals[jv*4+j] - mean) * rstd * g1[col] + be1[col]);
                }
                *(us4*)&hb[(size_t)tok * D_ + t8 * 24 + jv * 4] = o4;
            }
        }
    }
}

// ---------------------------------------------------------------------------
// Fused FF, swapped-operand (D = W.X): 64 tok/block, 512 thr, LDS 76.8 KB ->
// 2 blocks/CU. K32 double-buffered weight tiles via global_load_lds, prefetch
// before compute. Output fragment is [dcol][tok] -> us4 gelu writes, shfl-LN.
// ---------------------------------------------------------------------------
__global__ __launch_bounds__(512) void ff_mfma(
    us_t* __restrict__ hio,
    const us_t* __restrict__ WT, const float* __restrict__ b1,
    const float* __restrict__ b2,
    const float* __restrict__ gamma, const float* __restrict__ beta)
{
    __shared__ __align__(16) char smem[76800];
    us_t* Xs  = (us_t*)smem;               // [64][200]  25600 B
    us_t* Ts  = (us_t*)(smem + 25600);     // [64][200]  25600 B
    us_t* Wsb = (us_t*)(smem + 51200);     // [2][192][32] dbuf 24576 B
    float* Sm = (float*)(smem + 75776);    // [2][2][4][16] LN partials 1024 B

    const int tid = threadIdx.x;
    const int lane = tid & 63, wid = tid >> 6;
    const int g = lane >> 4, c = lane & 15;
    const int wr = wid >> 1;               // token block (16 rows)
    const int wc = wid & 1;                // dcol half (96 cols)
    const int row0 = blockIdx.x * 64;

    // stage one K32 weight image (12288 B = 12 chunks of 1024 B)
    auto stage = [&](int t) {
        const us_t* src = WT + (size_t)t * 6144;
        us_t* dst = Wsb + (t & 1) * 6144;
        for (int i = wid; i < 12; i += 8)
            gld16(src + i * 512 + lane * 8, dst + i * 512);
    };

    for (int e = tid; e < 1536; e += 512) {
        int tok = e / 24, v = e % 24;
        *(us8*)&Xs[tok * 200 + v * 8] = *(const us8*)&hio[(size_t)(row0 + tok) * D_ + v * 8];
    }
    stage(0);
    __syncthreads();

    f4 acc1[6], acc2[6];
    ZACC1(acc2, 6);
    for (int t = 0; t < 48; ++t) {
        const int s = t % 6, ph = (t / 6) & 1, cb = t / 12;
        if (t < 47) stage(t + 1);
        const us_t* W = Wsb + (t & 1) * 6144;
        if (!ph) {
            if (s == 0) ZACC1(acc1, 6);
            sh8 xb = *(const sh8*)&Xs[(16 * wr + c) * 200 + s * 32 + g * 8];
            #pragma unroll
            for (int ni = 0; ni < 6; ++ni) {
                sh8 wa = *(const sh8*)&W[(96 * wc + 16 * ni + c) * 32 + g * 8];
                acc1[ni] = MFMA(wa, xb, acc1[ni]);
            }
            if (s == 5) {                  // FF1 done for cb: bias+gelu -> Ts (us4)
                #pragma unroll
                for (int ni = 0; ni < 6; ++ni) {
                    const int d0 = 96 * wc + 16 * ni + 4 * g;
                    us4 o4;
                    #pragma unroll
                    for (int r = 0; r < 4; ++r)
                        o4[r] = f2bf(gelu_f(acc1[ni][r] + b1[cb * 192 + d0 + r]));
                    *(us4*)&Ts[(16 * wr + c) * 200 + d0] = o4;
                }
            }
        } else {
            sh8 tb = *(const sh8*)&Ts[(16 * wr + c) * 200 + s * 32 + g * 8];
            #pragma unroll
            for (int ni = 0; ni < 6; ++ni) {
                sh8 wa = *(const sh8*)&W[(96 * wc + 16 * ni + c) * 32 + g * 8];
                acc2[ni] = MFMA(wa, tb, acc2[ni]);
            }
        }
        __syncthreads();
    }

    // epilogue: acc2[ni][r] = OUT[dcol=96wc+16ni+4g+r][tok=16wr+c]
    float v[6][4];
    float sum = 0.f, ssq = 0.f;
    const int xrow = (16 * wr + c) * 200;
    #pragma unroll
    for (int ni = 0; ni < 6; ++ni)
        #pragma unroll
        for (int r = 0; r < 4; ++r) {
            const int dcol = 96 * wc + 16 * ni + 4 * g + r;
            float val = acc2[ni][r] + b2[dcol] + bf2f(Xs[xrow + dcol]);
            v[ni][r] = val; sum += val; ssq += val * val;
        }
    sum += __shfl_xor(sum, 16); sum += __shfl_xor(sum, 32);   // reduce over g
    ssq += __shfl_xor(ssq, 16); ssq += __shfl_xor(ssq, 32);
    if (g == 0) {
        Sm[((0 * 2 + wc) * 4 + wr) * 16 + c] = sum;
        Sm[((1 * 2 + wc) * 4 + wr) * 16 + c] = ssq;
    }
    __syncthreads();
    sum += Sm[((0 * 2 + (1 - wc)) * 4 + wr) * 16 + c];
    ssq += Sm[((1 * 2 + (1 - wc)) * 4 + wr) * 16 + c];
    const float mean = sum * (1.f / D_);
    const float var  = ssq * (1.f / D_) - mean * mean;
    const float rstd = rsqrtf(var + 1e-5f);
    us_t* orow = hio + (size_t)(row0 + 16 * wr + c) * D_;
    #pragma unroll
    for (int ni = 0; ni < 6; ++ni) {
        const int d0 = 96 * wc + 16 * ni + 4 * g;
        us4 o4;
        #pragma unroll
        for (int r = 0; r < 4; ++r)
            o4[r] = f2bf((v[ni][r] - mean) * rstd * gamma[d0 + r] + beta[d0 + r]);
        *(us4*)&orow[d0] = o4;
    }
}

// ---------------------------------------------------------------------------
// Classifier stage 1 (MFMA): hid = bf16(gelu(h @ Wc1 + bc1)). 64 tok/block.
// ---------------------------------------------------------------------------
__global__ __launch_bounds__(256) void clf1_mfma(
    const us_t* __restrict__ h, const us_t* __restrict__ Wc1t,
    const float* __restrict__ bc1, us_t* __restrict__ hid)
{
    __shared__ __align__(16) char smem[25600 + 13824];
    us_t* Xs = (us_t*)smem;              // [64][200]
    us_t* Ws = (us_t*)(smem + 25600);    // [96][72]
    const int tid = threadIdx.x;
    const int lane = tid & 63, wid = tid >> 6;
    const int g = lane >> 4, c = lane & 15;
    const int wr = wid >> 1, wc = wid & 1;
    const int row0 = blockIdx.x * 64;

    for (int e = tid; e < 1536; e += 256) {
        int tok = e / 24, v = e % 24;
        *(us8*)&Xs[tok * 200 + v * 8] = *(const us8*)&h[(size_t)(row0 + tok) * D_ + v * 8];
    }
    f4 acc[2][3];
    ZACC(acc, 2, 3);
    for (int pc = 0; pc < 3; ++pc) {
        __syncthreads();
        for (int e = tid; e < 768; e += 256) {
            int rw = e >> 3, v = e & 7;
            *(us8*)&Ws[rw * 72 + v * 8] =
                *(const us8*)&Wc1t[(size_t)rw * 192 + pc * 64 + v * 8];
        }
        __syncthreads();
        #pragma unroll
        for (int kk = 0; kk < 2; ++kk) {
            const int ka = pc * 64 + kk * 32 + g * 8;
            const int kw = kk * 32 + g * 8;
            sh8 a0 = *(const sh8*)&Xs[(32 * wr + c) * 200 + ka];
            sh8 a1 = *(const sh8*)&Xs[(32 * wr + 16 + c) * 200 + ka];
            #pragma unroll
            for (int ni = 0; ni < 3; ++ni) {
                sh8 bf = *(const sh8*)&Ws[(48 * wc + 16 * ni + c) * 72 + kw];
                acc[0][ni] = MFMA(a0, bf, acc[0][ni]);
                acc[1][ni] = MFMA(a1, bf, acc[1][ni]);
            }
        }
    }
    #pragma unroll
    for (int ni = 0; ni < 3; ++ni) {
        const int col = 48 * wc + 16 * ni + c;
        const float bv = bc1[col];
        #pragma unroll
        for (int mi = 0; mi < 2; ++mi)
            #pragma unroll
            for (int r = 0; r < 4; ++r) {
                int tok = row0 + 32 * wr + 16 * mi + 4 * g + r;
                hid[(size_t)tok * DH_ + col] = f2bf(gelu_f(acc[mi][ni][r] + bv));
            }
    }
}

// ---------------------------------------------------------------------------
// Classifier stage 2: out = hid @ Wc2 + bc2 (f32 VALU, tiny)
// ---------------------------------------------------------------------------
__global__ __launch_bounds__(256) void clf2_kernel(
    const us_t* __restrict__ hid, const float* __restrict__ Wc2,
    const float* __restrict__ bc2, float* __restrict__ out)
{
    __shared__ us_t Hs[64 * 104];
    __shared__ float Wl[DH_ * NC_];
    __shared__ float bl[NC_];
    const int tid = threadIdx.x;
    const int row0 = blockIdx.x * 64;
    for (int e = tid; e < 768; e += 256) {
        int tok = e / 12, v = e % 12;
        *(us8*)&Hs[tok * 104 + v * 8] = *(const us8*)&hid[(size_t)(row0 + tok) * DH_ + v * 8];
    }
    for (int e = tid; e < DH_ * NC_; e += 256) Wl[e] = Wc2[e];
    if (tid < NC_) bl[tid] = bc2[tid];
    __syncthreads();
    for (int e = tid; e < 64 * NC_; e += 256) {
        const int tok = e / NC_, col = e % NC_;
        float acc = bl[col];
        #pragma unroll 8
        for (int kk = 0; kk < DH_; ++kk)
            acc = fmaf(bf2f(Hs[tok * 104 + kk]), Wl[kk * NC_ + col], acc);
        out[(size_t)(row0 + tok) * NC_ + col] = acc;
    }
}

extern "C" void kernel_launch(void* const* d_in, const int* in_sizes, int n_in,
                              void* d_out, int out_size, void* d_ws, size_t ws_size,
                              hipStream_t stream)
{
    const float* x    = (const float*)d_in[0];
    const float* W_in = (const float*)d_in[1];
    const float* b_in = (const float*)d_in[2];
    const float* pe   = (const float*)d_in[3];
    const float* Wq   = (const float*)d_in[4];
    const float* bq   = (const float*)d_in[5];
    const float* Wk   = (const float*)d_in[6];
    const float* bk   = (const float*)d_in[7];
    const float* Wv   = (const float*)d_in[8];
    const float* bv   = (const float*)d_in[9];
    const float* Wo   = (const float*)d_in[10];
    const float* bo   = (const float*)d_in[11];
    const float* W1   = (const float*)d_in[12];
    const float* b1   = (const float*)d_in[13];
    const float* W2   = (const float*)d_in[14];
    const float* b2   = (const float*)d_in[15];
    const float* g1   = (const float*)d_in[16];
    const float* be1  = (const float*)d_in[17];
    const float* g2   = (const float*)d_in[18];
    const float* be2  = (const float*)d_in[19];
    const float* Wc1  = (const float*)d_in[20];
    const float* bc1  = (const float*)d_in[21];
    const float* Wc2  = (const float*)d_in[22];
    const float* bc2  = (const float*)d_in[23];
    float* outp = (float*)d_out;

    // ws layout (us_t elems): h | hid | Wint | Wq/k/v/ot | WT(ff) | Wc1t
    us_t* h    = (us_t*)d_ws;
    us_t* hid  = h + (size_t)NTOK * D_;
    us_t* Wint = hid + (size_t)NTOK * DH_;
    us_t* Wqt  = Wint + 192 * 224;
    us_t* Wkt  = Wqt + 3 * 36864;
    us_t* Wvt  = Wkt + 3 * 36864;
    us_t* Wot  = Wvt + 3 * 36864;
    us_t* WT   = Wot + 3 * 36864;
    us_t* Wc1t = WT + (size_t)L_ * 48 * 6144;

    // ---- weight prep ----
    prep_t<<<168, 256, 0, stream>>>(W_in, Wint, IND_, 224, D_);
    for (int l = 0; l < L_; ++l) {
        prep_t<<<144, 256, 0, stream>>>(Wq + (size_t)l * 36864, Wqt + (size_t)l * 36864, 192, 192, 192);
        prep_t<<<144, 256, 0, stream>>>(Wk + (size_t)l * 36864, Wkt + (size_t)l * 36864, 192, 192, 192);
        prep_t<<<144, 256, 0, stream>>>(Wv + (size_t)l * 36864, Wvt + (size_t)l * 36864, 192, 192, 192);
        prep_t<<<144, 256, 0, stream>>>(Wo + (size_t)l * 36864, Wot + (size_t)l * 36864, 192, 192, 192);
    }
    prep_ff<<<(L_ * 48 * 6144 + 255) / 256, 256, 0, stream>>>(W1, W2, WT);
    prep_t<<<72, 256, 0, stream>>>(Wc1, Wc1t, 192, 192, DH_);

    // ---- forward ----
    inp_mfma<<<NTOK / 64, 256, 0, stream>>>(x, Wint, b_in, pe, h);

    for (int l = 0; l < L_; ++l) {
        qkv_attn_wo<<<B_, 512, 0, stream>>>(
            h,
            Wqt + (size_t)l * 36864, Wkt + (size_t)l * 36864,
            Wvt + (size_t)l * 36864, Wot + (size_t)l * 36864,
            bq + l * D_, bk + l * D_, bv + l * D_, bo + l * D_,
            g1 + l * D_, be1 + l * D_);
        ff_mfma<<<NTOK / 64, 512, 0, stream>>>(
            h, WT + (size_t)l * 48 * 6144, b1 + l * DFF_, b2 + l * D_,
            g2 + l * D_, be2 + l * D_);
    }

    clf1_mfma<<<NTOK / 64, 256, 0, stream>>>(h, Wc1t, bc1, hid);
    clf2_kernel<<<NTOK / 64, 256, 0, stream>>>(hid, Wc2, bc2, outp);
}

// Round 8
// 1264.627 us; speedup vs baseline: 1.0665x; 1.0665x over previous
//
#include <hip/hip_runtime.h>
#include <cmath>

#define B_   2048
#define S_   60
#define NTOK (B_*S_)
#define IND_ 211
#define D_   192
#define H_   6
#define DK_  32
#define L_   3
#define DFF_ 768
#define NC_  35
#define DH_  96

typedef unsigned short us_t;
typedef us_t us8 __attribute__((ext_vector_type(8)));
typedef us_t us4 __attribute__((ext_vector_type(4)));
typedef short sh8 __attribute__((ext_vector_type(8)));
typedef float f4 __attribute__((ext_vector_type(4)));

#define MFMA(a, b, cc) __builtin_amdgcn_mfma_f32_16x16x32_bf16((a), (b), (cc), 0, 0, 0)
#define ZACC(A, M, N) \
    for (int _i = 0; _i < (M); ++_i) \
        for (int _j = 0; _j < (N); ++_j) { \
            A[_i][_j][0] = 0.f; A[_i][_j][1] = 0.f; A[_i][_j][2] = 0.f; A[_i][_j][3] = 0.f; }
#define ZACC1(A, N) \
    for (int _j = 0; _j < (N); ++_j) { \
        A[_j][0] = 0.f; A[_j][1] = 0.f; A[_j][2] = 0.f; A[_j][3] = 0.f; }

__device__ __forceinline__ float bf2f(us_t u) {
    union { unsigned int i; float f; } v; v.i = ((unsigned int)u) << 16; return v.f;
}
__device__ __forceinline__ us_t f2bf(float f) {
    union { float f; unsigned int i; } v; v.f = f;
    unsigned int r = v.i + 0x7fffu + ((v.i >> 16) & 1u);
    return (us_t)(r >> 16);
}
// fast tanh-gelu: |err| < 1e-3 vs exact erf-gelu, well under bf16 rounding
__device__ __forceinline__ float gelu_f(float v) {
    float u = v * (0.7978845608f + 0.0356774081f * v * v);
    float e = __expf(2.f * u);
    float t = 1.f - 2.f / (e + 1.f);       // overflow-safe tanh
    return 0.5f * v * (1.f + t);
}
__device__ __forceinline__ void gld16(const us_t* g, us_t* s) {
    __builtin_amdgcn_global_load_lds(
        (const __attribute__((address_space(1))) unsigned int*)(g),
        (__attribute__((address_space(3))) unsigned int*)(s), 16, 0, 0);
}

// ---------------------------------------------------------------------------
// Weight prep (qkv/wo/inp/clf1): out[n][kp] = bf16(in[kp][n]), zero-pad Kpad.
// ---------------------------------------------------------------------------
__global__ void prep_t(const float* __restrict__ in, us_t* __restrict__ out,
                       int K, int Kpad, int N)
{
    int e = blockIdx.x * 256 + threadIdx.x;
    if (e >= N * Kpad) return;
    int n = e / Kpad, kp = e % Kpad;
    out[e] = (kp < K) ? f2bf(in[(size_t)kp * N + n]) : (us_t)0;
}

// ---------------------------------------------------------------------------
// FF weight prep: 48 K32-subtile images per layer, consumption order.
// t = cb*12 + ph*6 + s; image [192 cols][40 us_t] (stride-40 pad, 15360 B).
// Bank pattern of fragment reads: (20c+4g)%32 -> exactly 8/bank = min.
// ---------------------------------------------------------------------------
__global__ void prep_ff(const float* __restrict__ W1, const float* __restrict__ W2,
                        us_t* __restrict__ WT)
{
    int e = blockIdx.x * 256 + threadIdx.x;
    if (e >= L_ * 48 * 7680) return;
    int l = e / (48 * 7680), r = e % (48 * 7680);
    int t = r / 7680, q = r % 7680;
    int col = q / 40, kk = q % 40;
    int cb = t / 12, ph = (t / 6) & 1, s = t % 6;
    us_t v = 0;
    if (kk < 32) {
        if (!ph) v = f2bf(W1[((size_t)l * D_ + s * 32 + kk) * DFF_ + cb * 192 + col]);
        else     v = f2bf(W2[((size_t)l * DFF_ + cb * 192 + s * 32 + kk) * D_ + col]);
    }
    WT[e] = v;
}

// ---------------------------------------------------------------------------
// Input projection: h = bf16(x @ W_in + b_in + pe). 64 tok/block, 4 waves.
// ---------------------------------------------------------------------------
__global__ __launch_bounds__(256) void inp_mfma(
    const float* __restrict__ x, const us_t* __restrict__ Wint,
    const float* __restrict__ b_in, const float* __restrict__ pe,
    us_t* __restrict__ h)
{
    __shared__ __align__(16) char smem[29696 + 27648];
    us_t* Xs = (us_t*)smem;              // [64][232]
    us_t* Ws = (us_t*)(smem + 29696);    // [192][72]
    const int tid = threadIdx.x;
    const int lane = tid & 63, wid = tid >> 6;
    const int g = lane >> 4, c = lane & 15;
    const int wr = wid >> 1, wc = wid & 1;
    const int row0 = blockIdx.x * 64;

    for (int e = tid; e < 64 * 224; e += 256) {
        int tok = e / 224, kp = e % 224;
        float v = (kp < IND_) ? x[(size_t)(row0 + tok) * IND_ + kp] : 0.f;
        Xs[tok * 232 + kp] = f2bf(v);
    }

    f4 acc[2][6];
    ZACC(acc, 2, 6);
    for (int pc = 0; pc < 4; ++pc) {
        __syncthreads();
        const int nk = (pc < 3) ? 64 : 32;
        const int per = nk / 8;
        for (int e = tid; e < 192 * per; e += 256) {
            int rw = e / per, v = e % per;
            *(us8*)&Ws[rw * 72 + v * 8] =
                *(const us8*)&Wint[(size_t)rw * 224 + pc * 64 + v * 8];
        }
        __syncthreads();
        for (int kk = 0; kk < nk / 32; ++kk) {
            const int ka = pc * 64 + kk * 32 + g * 8;
            const int kw = kk * 32 + g * 8;
            sh8 a0 = *(const sh8*)&Xs[(32 * wr + c) * 232 + ka];
            sh8 a1 = *(const sh8*)&Xs[(32 * wr + 16 + c) * 232 + ka];
            #pragma unroll
            for (int ni = 0; ni < 6; ++ni) {
                sh8 bf = *(const sh8*)&Ws[(96 * wc + 16 * ni + c) * 72 + kw];
                acc[0][ni] = MFMA(a0, bf, acc[0][ni]);
                acc[1][ni] = MFMA(a1, bf, acc[1][ni]);
            }
        }
    }
    #pragma unroll
    for (int ni = 0; ni < 6; ++ni) {
        const int col = 96 * wc + 16 * ni + c;
        const float bv = b_in[col];
        #pragma unroll
        for (int mi = 0; mi < 2; ++mi)
            #pragma unroll
            for (int r = 0; r < 4; ++r) {
                int tokg = row0 + 32 * wr + 16 * mi + 4 * g + r;
                int s = tokg % S_;
                float val = acc[mi][ni][r] + bv + pe[(size_t)s * D_ + col];
                h[(size_t)tokg * D_ + col] = f2bf(val);
            }
    }
}

// ---------------------------------------------------------------------------
// Fused QKV + attention + Wo + residual + LN. One 512-thread block per batch.
// ---------------------------------------------------------------------------
__global__ __launch_bounds__(512) void qkv_attn_wo(
    us_t* __restrict__ h,
    const us_t* __restrict__ Wqt, const us_t* __restrict__ Wkt,
    const us_t* __restrict__ Wvt, const us_t* __restrict__ Wot,
    const float* __restrict__ bq, const float* __restrict__ bk,
    const float* __restrict__ bv, const float* __restrict__ bo,
    const float* __restrict__ g1, const float* __restrict__ be1)
{
    __shared__ __align__(16) char smem[157696];
    us_t* Xs = (us_t*)smem;               // [64][200]
    us_t* Qs = (us_t*)(smem + 25600);     // [64][200]
    us_t* Ks = (us_t*)(smem + 51200);     // [64][200]
    us_t* Vt = (us_t*)(smem + 76800);     // [192][72] (V transposed)
    us_t* Ws = (us_t*)(smem + 104448);    // [192][72]
    us_t* P0 = (us_t*)(smem + 104448);    // [64][72] overlays Ws
    us_t* P1 = (us_t*)(smem + 113664);    // [64][72]
    us_t* Cx = (us_t*)(smem + 132096);    // [64][200]
    float* eL = (float*)(smem + 51200);   // [64][200] f32 overlays Ks+Vt

    const int tid = threadIdx.x;
    const int lane = tid & 63, wid = tid >> 6;
    const int g = lane >> 4, c = lane & 15;
    const int wr = wid >> 2, wc = wid & 3;
    us_t* hb = h + (size_t)blockIdx.x * (S_ * D_);

    for (int e = tid; e < 1536; e += 512) {
        int tok = e / 24, v = e % 24;
        us8 u = {0, 0, 0, 0, 0, 0, 0, 0};
        if (tok < S_) u = *(const us8*)&hb[(size_t)tok * D_ + v * 8];
        *(us8*)&Xs[tok * 200 + v * 8] = u;
    }

    for (int m = 0; m < 3; ++m) {
        const us_t* Wt = (m == 0) ? Wqt : (m == 1) ? Wkt : Wvt;
        const float* bb = (m == 0) ? bq : (m == 1) ? bk : bv;
        f4 acc[2][3];
        ZACC(acc, 2, 3);
        for (int pc = 0; pc < 3; ++pc) {
            __syncthreads();
            for (int e = tid; e < 1536; e += 512) {
                int rw = e >> 3, v = e & 7;
                *(us8*)&Ws[rw * 72 + v * 8] =
                    *(const us8*)&Wt[(size_t)rw * 192 + pc * 64 + v * 8];
            }
            __syncthreads();
            #pragma unroll
            for (int kk = 0; kk < 2; ++kk) {
                const int ka = pc * 64 + kk * 32 + g * 8;
                const int kw = kk * 32 + g * 8;
                sh8 a0 = *(const sh8*)&Xs[(32 * wr + c) * 200 + ka];
                sh8 a1 = *(const sh8*)&Xs[(32 * wr + 16 + c) * 200 + ka];
                #pragma unroll
                for (int ni = 0; ni < 3; ++ni) {
                    sh8 bf = *(const sh8*)&Ws[(48 * wc + 16 * ni + c) * 72 + kw];
                    acc[0][ni] = MFMA(a0, bf, acc[0][ni]);
                    acc[1][ni] = MFMA(a1, bf, acc[1][ni]);
                }
            }
        }
        #pragma unroll
        for (int ni = 0; ni < 3; ++ni) {
            const int col = 48 * wc + 16 * ni + c;
            const float bval = bb[col];
            #pragma unroll
            for (int mi = 0; mi < 2; ++mi)
                #pragma unroll
                for (int r = 0; r < 4; ++r) {
                    int tok = 32 * wr + 16 * mi + 4 * g + r;
                    us_t o = f2bf(acc[mi][ni][r] + bval);
                    if (m == 0)      Qs[tok * 200 + col] = o;
                    else if (m == 1) Ks[tok * 200 + col] = o;
                    else             Vt[col * 72 + tok] = o;
                }
        }
    }
    __syncthreads();

    const int hgrp = wid & 3;
    const int hsel = wid >> 2;
    for (int rr = 0; rr < 3; ++rr) {
        const int hh = 2 * rr + hsel;
        us_t* Pb = hsel ? P1 : P0;
        f4 sc[4];
        ZACC1(sc, 4);
        {
            const int ka = 32 * hh + g * 8;
            sh8 aq = *(const sh8*)&Qs[(16 * hgrp + c) * 200 + ka];
            #pragma unroll
            for (int ni = 0; ni < 4; ++ni) {
                sh8 bk8 = *(const sh8*)&Ks[(16 * ni + c) * 200 + ka];
                sc[ni] = MFMA(aq, bk8, sc[ni]);
            }
        }
        #pragma unroll
        for (int r = 0; r < 4; ++r) {
            float mx = -1e30f;
            #pragma unroll
            for (int ni = 0; ni < 4; ++ni) {
                float v = sc[ni][r] * 0.17677669529663687f;
                if (16 * ni + c >= S_) v = -1e30f;
                sc[ni][r] = v;
                mx = fmaxf(mx, v);
            }
            mx = fmaxf(mx, __shfl_xor(mx, 1));
            mx = fmaxf(mx, __shfl_xor(mx, 2));
            mx = fmaxf(mx, __shfl_xor(mx, 4));
            mx = fmaxf(mx, __shfl_xor(mx, 8));
            float sum = 0.f;
            #pragma unroll
            for (int ni = 0; ni < 4; ++ni) {
                float e = __expf(sc[ni][r] - mx);
                sc[ni][r] = e; sum += e;
            }
            sum += __shfl_xor(sum, 1);
            sum += __shfl_xor(sum, 2);
            sum += __shfl_xor(sum, 4);
            sum += __shfl_xor(sum, 8);
            const float inv = 1.f / sum;
            #pragma unroll
            for (int ni = 0; ni < 4; ++ni)
                Pb[(16 * hgrp + 4 * g + r) * 72 + 16 * ni + c] = f2bf(sc[ni][r] * inv);
        }
        __syncthreads();
        f4 ov[2];
        ZACC1(ov, 2);
        #pragma unroll
        for (int kk = 0; kk < 2; ++kk) {
            sh8 ap = *(const sh8*)&Pb[(16 * hgrp + c) * 72 + kk * 32 + g * 8];
            #pragma unroll
            for (int n2 = 0; n2 < 2; ++n2) {
                sh8 bv8 = *(const sh8*)&Vt[(32 * hh + 16 * n2 + c) * 72 + kk * 32 + g * 8];
                ov[n2] = MFMA(ap, bv8, ov[n2]);
            }
        }
        #pragma unroll
        for (int n2 = 0; n2 < 2; ++n2)
            #pragma unroll
            for (int r = 0; r < 4; ++r)
                Cx[(16 * hgrp + 4 * g + r) * 200 + 32 * hh + 16 * n2 + c] = f2bf(ov[n2][r]);
        __syncthreads();
    }

    f4 aw[2][3];
    ZACC(aw, 2, 3);
    for (int pc = 0; pc < 3; ++pc) {
        __syncthreads();
        for (int e = tid; e < 1536; e += 512) {
            int rw = e >> 3, v = e & 7;
            *(us8*)&Ws[rw * 72 + v * 8] =
                *(const us8*)&Wot[(size_t)rw * 192 + pc * 64 + v * 8];
        }
        __syncthreads();
        #pragma unroll
        for (int kk = 0; kk < 2; ++kk) {
            const int ka = pc * 64 + kk * 32 + g * 8;
            const int kw = kk * 32 + g * 8;
            sh8 a0 = *(const sh8*)&Cx[(32 * wr + c) * 200 + ka];
            sh8 a1 = *(const sh8*)&Cx[(32 * wr + 16 + c) * 200 + ka];
            #pragma unroll
            for (int ni = 0; ni < 3; ++ni) {
                sh8 bf = *(const sh8*)&Ws[(48 * wc + 16 * ni + c) * 72 + kw];
                aw[0][ni] = MFMA(a0, bf, aw[0][ni]);
                aw[1][ni] = MFMA(a1, bf, aw[1][ni]);
            }
        }
    }
    __syncthreads();
    #pragma unroll
    for (int ni = 0; ni < 3; ++ni) {
        const int col = 48 * wc + 16 * ni + c;
        const float bov = bo[col];
        #pragma unroll
        for (int mi = 0; mi < 2; ++mi)
            #pragma unroll
            for (int r = 0; r < 4; ++r) {
                int tok = 32 * wr + 16 * mi + 4 * g + r;
                eL[tok * 200 + col] = aw[mi][ni][r] + bov + bf2f(Xs[tok * 200 + col]);
            }
    }
    __syncthreads();
    {
        const int tok = tid >> 3, t8 = tid & 7;
        float vals[24], sum = 0.f, ssq = 0.f;
        #pragma unroll
        for (int jv = 0; jv < 6; ++jv) {
            float4 v4 = *(const float4*)&eL[tok * 200 + t8 * 24 + jv * 4];
            vals[jv*4+0] = v4.x; vals[jv*4+1] = v4.y; vals[jv*4+2] = v4.z; vals[jv*4+3] = v4.w;
            sum += v4.x + v4.y + v4.z + v4.w;
            ssq += v4.x*v4.x + v4.y*v4.y + v4.z*v4.z + v4.w*v4.w;
        }
        sum += __shfl_xor(sum, 1); sum += __shfl_xor(sum, 2); sum += __shfl_xor(sum, 4);
        ssq += __shfl_xor(ssq, 1); ssq += __shfl_xor(ssq, 2); ssq += __shfl_xor(ssq, 4);
        const float mean = sum * (1.f / D_);
        const float var  = ssq * (1.f / D_) - mean * mean;
        const float rstd = rsqrtf(var + 1e-5f);
        if (tok < S_) {
            #pragma unroll
            for (int jv = 0; jv < 6; ++jv) {
                us4 o4;
                #pragma unroll
                for (int j = 0; j < 4; ++j) {
                    int col = t8 * 24 + jv * 4 + j;
                    o4[j] = f2bf((vals[jv*4+j] - mean) * rstd * g1[col] + be1[col]);
                }
                *(us4*)&hb[(size_t)tok * D_ + t8 * 24 + jv * 4] = o4;
            }
        }
    }
}

// ---------------------------------------------------------------------------
// Fused FF, swapped-operand, balanced wave split: 64 tok/block, 512 thr,
// 4 col-groups (ni=3) x 2 tok-groups (mi=2) -> 6 MFMA per 5 b128 reads.
// W tiles stride-40 (conflict-free), dbuf via global_load_lds.
// LDS exactly 80 KB -> 2 blocks/CU.
// ---------------------------------------------------------------------------
__global__ __launch_bounds__(512) void ff_mfma(
    us_t* __restrict__ hio,
    const us_t* __restrict__ WT, const float* __restrict__ b1,
    const float* __restrict__ b2,
    const float* __restrict__ gamma, const float* __restrict__ beta)
{
    __shared__ __align__(16) char smem[81920];
    us_t* Xs  = (us_t*)smem;               // [64][200]  25600 B
    us_t* Ts  = (us_t*)(smem + 25600);     // [64][200]  25600 B
    us_t* Wsb = (us_t*)(smem + 51200);     // [2][192][40] dbuf 30720 B
    float* Sm = (float*)(smem + 25600);    // LN partials overlay Ts

    const int tid = threadIdx.x;
    const int lane = tid & 63, wid = tid >> 6;
    const int g = lane >> 4, c = lane & 15;
    const int wr = wid >> 2;               // token group (32 rows)
    const int wc = wid & 3;                // col group (48 cols)
    const int row0 = blockIdx.x * 64;

    // stage one K32 weight image (15360 B = 15 chunks of 1024 B)
    auto stage = [&](int t) {
        const us_t* src = WT + (size_t)t * 7680;
        us_t* dst = Wsb + (t & 1) * 7680;
        for (int i = wid; i < 15; i += 8)
            gld16(src + i * 512 + lane * 8, dst + i * 512);
    };

    for (int e = tid; e < 1536; e += 512) {
        int tok = e / 24, v = e % 24;
        *(us8*)&Xs[tok * 200 + v * 8] = *(const us8*)&hio[(size_t)(row0 + tok) * D_ + v * 8];
    }
    stage(0);
    __syncthreads();

    f4 acc1[2][3], acc2[2][3];
    ZACC(acc2, 2, 3);
    for (int t = 0; t < 48; ++t) {
        const int s = t % 6, ph = (t / 6) & 1, cb = t / 12;
        if (t < 47) stage(t + 1);
        const us_t* W = Wsb + (t & 1) * 7680;
        if (!ph) {
            if (s == 0) ZACC(acc1, 2, 3);
            sh8 xb0 = *(const sh8*)&Xs[(32 * wr + c) * 200 + s * 32 + g * 8];
            sh8 xb1 = *(const sh8*)&Xs[(32 * wr + 16 + c) * 200 + s * 32 + g * 8];
            #pragma unroll
            for (int ni = 0; ni < 3; ++ni) {
                sh8 wa = *(const sh8*)&W[(48 * wc + 16 * ni + c) * 40 + g * 8];
                acc1[0][ni] = MFMA(wa, xb0, acc1[0][ni]);
                acc1[1][ni] = MFMA(wa, xb1, acc1[1][ni]);
            }
            if (s == 5) {                  // FF1 done for cb: bias+gelu -> Ts (us4)
                #pragma unroll
                for (int mi = 0; mi < 2; ++mi)
                    #pragma unroll
                    for (int ni = 0; ni < 3; ++ni) {
                        const int d0 = 48 * wc + 16 * ni + 4 * g;
                        const int tok = 32 * wr + 16 * mi + c;
                        us4 o4;
                        #pragma unroll
                        for (int r = 0; r < 4; ++r)
                            o4[r] = f2bf(gelu_f(acc1[mi][ni][r] + b1[cb * 192 + d0 + r]));
                        *(us4*)&Ts[tok * 200 + d0] = o4;
                    }
            }
        } else {
            sh8 tb0 = *(const sh8*)&Ts[(32 * wr + c) * 200 + s * 32 + g * 8];
            sh8 tb1 = *(const sh8*)&Ts[(32 * wr + 16 + c) * 200 + s * 32 + g * 8];
            #pragma unroll
            for (int ni = 0; ni < 3; ++ni) {
                sh8 wa = *(const sh8*)&W[(48 * wc + 16 * ni + c) * 40 + g * 8];
                acc2[0][ni] = MFMA(wa, tb0, acc2[0][ni]);
                acc2[1][ni] = MFMA(wa, tb1, acc2[1][ni]);
            }
        }
        __syncthreads();
    }

    // epilogue: acc2[mi][ni][r] = OUT[dcol=48wc+16ni+4g+r][tok=32wr+16mi+c]
    float v[2][3][4];
    float sum[2] = {0.f, 0.f}, ssq[2] = {0.f, 0.f};
    #pragma unroll
    for (int mi = 0; mi < 2; ++mi) {
        const int tok = 32 * wr + 16 * mi + c;
        #pragma unroll
        for (int ni = 0; ni < 3; ++ni) {
            const int d0 = 48 * wc + 16 * ni + 4 * g;
            us4 rv = *(const us4*)&Xs[tok * 200 + d0];
            #pragma unroll
            for (int r = 0; r < 4; ++r) {
                float val = acc2[mi][ni][r] + b2[d0 + r] + bf2f(rv[r]);
                v[mi][ni][r] = val; sum[mi] += val; ssq[mi] += val * val;
            }
        }
    }
    #pragma unroll
    for (int mi = 0; mi < 2; ++mi) {
        sum[mi] += __shfl_xor(sum[mi], 16); sum[mi] += __shfl_xor(sum[mi], 32);
        ssq[mi] += __shfl_xor(ssq[mi], 16); ssq[mi] += __shfl_xor(ssq[mi], 32);
    }
    if (g == 0) {
        #pragma unroll
        for (int mi = 0; mi < 2; ++mi) {
            Sm[(((0 * 4 + wc) * 2 + wr) * 2 + mi) * 16 + c] = sum[mi];
            Sm[(((1 * 4 + wc) * 2 + wr) * 2 + mi) * 16 + c] = ssq[mi];
        }
    }
    __syncthreads();
    #pragma unroll
    for (int mi = 0; mi < 2; ++mi) {
        float st = 0.f, qt = 0.f;
        #pragma unroll
        for (int w = 0; w < 4; ++w) {
            st += Sm[(((0 * 4 + w) * 2 + wr) * 2 + mi) * 16 + c];
            qt += Sm[(((1 * 4 + w) * 2 + wr) * 2 + mi) * 16 + c];
        }
        const float mean = st * (1.f / D_);
        const float var  = qt * (1.f / D_) - mean * mean;
        const float rstd = rsqrtf(var + 1e-5f);
        const int tok = 32 * wr + 16 * mi + c;
        us_t* orow = hio + (size_t)(row0 + tok) * D_;
        #pragma unroll
        for (int ni = 0; ni < 3; ++ni) {
            const int d0 = 48 * wc + 16 * ni + 4 * g;
            us4 o4;
            #pragma unroll
            for (int r = 0; r < 4; ++r)
                o4[r] = f2bf((v[mi][ni][r] - mean) * rstd * gamma[d0 + r] + beta[d0 + r]);
            *(us4*)&orow[d0] = o4;
        }
    }
}

// ---------------------------------------------------------------------------
// Classifier stage 1 (MFMA): hid = bf16(gelu(h @ Wc1 + bc1)). 64 tok/block.
// ---------------------------------------------------------------------------
__global__ __launch_bounds__(256) void clf1_mfma(
    const us_t* __restrict__ h, const us_t* __restrict__ Wc1t,
    const float* __restrict__ bc1, us_t* __restrict__ hid)
{
    __shared__ __align__(16) char smem[25600 + 13824];
    us_t* Xs = (us_t*)smem;              // [64][200]
    us_t* Ws = (us_t*)(smem + 25600);    // [96][72]
    const int tid = threadIdx.x;
    const int lane = tid & 63, wid = tid >> 6;
    const int g = lane >> 4, c = lane & 15;
    const int wr = wid >> 1, wc = wid & 1;
    const int row0 = blockIdx.x * 64;

    for (int e = tid; e < 1536; e += 256) {
        int tok = e / 24, v = e % 24;
        *(us8*)&Xs[tok * 200 + v * 8] = *(const us8*)&h[(size_t)(row0 + tok) * D_ + v * 8];
    }
    f4 acc[2][3];
    ZACC(acc, 2, 3);
    for (int pc = 0; pc < 3; ++pc) {
        __syncthreads();
        for (int e = tid; e < 768; e += 256) {
            int rw = e >> 3, v = e & 7;
            *(us8*)&Ws[rw * 72 + v * 8] =
                *(const us8*)&Wc1t[(size_t)rw * 192 + pc * 64 + v * 8];
        }
        __syncthreads();
        #pragma unroll
        for (int kk = 0; kk < 2; ++kk) {
            const int ka = pc * 64 + kk * 32 + g * 8;
            const int kw = kk * 32 + g * 8;
            sh8 a0 = *(const sh8*)&Xs[(32 * wr + c) * 200 + ka];
            sh8 a1 = *(const sh8*)&Xs[(32 * wr + 16 + c) * 200 + ka];
            #pragma unroll
            for (int ni = 0; ni < 3; ++ni) {
                sh8 bf = *(const sh8*)&Ws[(48 * wc + 16 * ni + c) * 72 + kw];
                acc[0][ni] = MFMA(a0, bf, acc[0][ni]);
                acc[1][ni] = MFMA(a1, bf, acc[1][ni]);
            }
        }
    }
    #pragma unroll
    for (int ni = 0; ni < 3; ++ni) {
        const int col = 48 * wc + 16 * ni + c;
        const float bv = bc1[col];
        #pragma unroll
        for (int mi = 0; mi < 2; ++mi)
            #pragma unroll
            for (int r = 0; r < 4; ++r) {
                int tok = row0 + 32 * wr + 16 * mi + 4 * g + r;
                hid[(size_t)tok * DH_ + col] = f2bf(gelu_f(acc[mi][ni][r] + bv));
            }
    }
}

// ---------------------------------------------------------------------------
// Classifier stage 2: out = hid @ Wc2 + bc2 (f32 VALU, tiny)
// ---------------------------------------------------------------------------
__global__ __launch_bounds__(256) void clf2_kernel(
    const us_t* __restrict__ hid, const float* __restrict__ Wc2,
    const float* __restrict__ bc2, float* __restrict__ out)
{
    __shared__ us_t Hs[64 * 104];
    __shared__ float Wl[DH_ * NC_];
    __shared__ float bl[NC_];
    const int tid = threadIdx.x;
    const int row0 = blockIdx.x * 64;
    for (int e = tid; e < 768; e += 256) {
        int tok = e / 12, v = e % 12;
        *(us8*)&Hs[tok * 104 + v * 8] = *(const us8*)&hid[(size_t)(row0 + tok) * DH_ + v * 8];
    }
    for (int e = tid; e < DH_ * NC_; e += 256) Wl[e] = Wc2[e];
    if (tid < NC_) bl[tid] = bc2[tid];
    __syncthreads();
    for (int e = tid; e < 64 * NC_; e += 256) {
        const int tok = e / NC_, col = e % NC_;
        float acc = bl[col];
        #pragma unroll 8
        for (int kk = 0; kk < DH_; ++kk)
            acc = fmaf(bf2f(Hs[tok * 104 + kk]), Wl[kk * NC_ + col], acc);
        out[(size_t)(row0 + tok) * NC_ + col] = acc;
    }
}

extern "C" void kernel_launch(void* const* d_in, const int* in_sizes, int n_in,
                              void* d_out, int out_size, void* d_ws, size_t ws_size,
                              hipStream_t stream)
{
    const float* x    = (const float*)d_in[0];
    const float* W_in = (const float*)d_in[1];
    const float* b_in = (const float*)d_in[2];
    const float* pe   = (const float*)d_in[3];
    const float* Wq   = (const float*)d_in[4];
    const float* bq   = (const float*)d_in[5];
    const float* Wk   = (const float*)d_in[6];
    const float* bk   = (const float*)d_in[7];
    const float* Wv   = (const float*)d_in[8];
    const float* bv   = (const float*)d_in[9];
    const float* Wo   = (const float*)d_in[10];
    const float* bo   = (const float*)d_in[11];
    const float* W1   = (const float*)d_in[12];
    const float* b1   = (const float*)d_in[13];
    const float* W2   = (const float*)d_in[14];
    const float* b2   = (const float*)d_in[15];
    const float* g1   = (const float*)d_in[16];
    const float* be1  = (const float*)d_in[17];
    const float* g2   = (const float*)d_in[18];
    const float* be2  = (const float*)d_in[19];
    const float* Wc1  = (const float*)d_in[20];
    const float* bc1  = (const float*)d_in[21];
    const float* Wc2  = (const float*)d_in[22];
    const float* bc2  = (const float*)d_in[23];
    float* outp = (float*)d_out;

    // ws layout (us_t elems): h | hid | Wint | Wq/k/v/ot | WT(ff) | Wc1t
    us_t* h    = (us_t*)d_ws;
    us_t* hid  = h + (size_t)NTOK * D_;
    us_t* Wint = hid + (size_t)NTOK * DH_;
    us_t* Wqt  = Wint + 192 * 224;
    us_t* Wkt  = Wqt + 3 * 36864;
    us_t* Wvt  = Wkt + 3 * 36864;
    us_t* Wot  = Wvt + 3 * 36864;
    us_t* WT   = Wot + 3 * 36864;
    us_t* Wc1t = WT + (size_t)L_ * 48 * 7680;

    // ---- weight prep ----
    prep_t<<<168, 256, 0, stream>>>(W_in, Wint, IND_, 224, D_);
    for (int l = 0; l < L_; ++l) {
        prep_t<<<144, 256, 0, stream>>>(Wq + (size_t)l * 36864, Wqt + (size_t)l * 36864, 192, 192, 192);
        prep_t<<<144, 256, 0, stream>>>(Wk + (size_t)l * 36864, Wkt + (size_t)l * 36864, 192, 192, 192);
        prep_t<<<144, 256, 0, stream>>>(Wv + (size_t)l * 36864, Wvt + (size_t)l * 36864, 192, 192, 192);
        prep_t<<<144, 256, 0, stream>>>(Wo + (size_t)l * 36864, Wot + (size_t)l * 36864, 192, 192, 192);
    }
    prep_ff<<<(L_ * 48 * 7680 + 255) / 256, 256, 0, stream>>>(W1, W2, WT);
    prep_t<<<72, 256, 0, stream>>>(Wc1, Wc1t, 192, 192, DH_);

    // ---- forward ----
    inp_mfma<<<NTOK / 64, 256, 0, stream>>>(x, Wint, b_in, pe, h);

    for (int l = 0; l < L_; ++l) {
        qkv_attn_wo<<<B_, 512, 0, stream>>>(
            h,
            Wqt + (size_t)l * 36864, Wkt + (size_t)l * 36864,
            Wvt + (size_t)l * 36864, Wot + (size_t)l * 36864,
            bq + l * D_, bk + l * D_, bv + l * D_, bo + l * D_,
            g1 + l * D_, be1 + l * D_);
        ff_mfma<<<NTOK / 64, 512, 0, stream>>>(
            h, WT + (size_t)l * 48 * 7680, b1 + l * DFF_, b2 + l * D_,
            g2 + l * D_, be2 + l * D_);
    }

    clf1_mfma<<<NTOK / 64, 256, 0, stream>>>(h, Wc1t, bc1, hid);
    clf2_kernel<<<NTOK / 64, 256, 0, stream>>>(hid, Wc2, bc2, outp);
}